// Round 6
// baseline (943.125 us; speedup 1.0000x reference)
//
#include <hip/hip_runtime.h>
#include <stdint.h>

#define NROWS 8192
#define DIM 128
#define NTILE 528    // 32x32 upper triangle of 256x256 tiles
// DIAGNOSTIC: process each tile REPEAT times (bit-idempotent P/Q stores).
// Purpose: lift gram above the 41.5us fill cutoff so rocprof top-5 finally
// shows its counters, and discriminate cold-latency vs structural stall:
// dur ~= REPEAT * warm_rep  => structural;  dur << REPEAT * 34us => latency.
// Set to 1 once diagnosed.
#define REPEAT 16

typedef __bf16 bf16x8 __attribute__((ext_vector_type(8)));
typedef float floatx4 __attribute__((ext_vector_type(4)));

// ---------- helpers ----------
static __device__ __forceinline__ unsigned short f2bf(float f) {
    unsigned int u = __float_as_uint(f);
    unsigned int r = (u + 0x7FFFu + ((u >> 16) & 1u)) >> 16;   // RNE
    return (unsigned short)r;
}

// XOR swizzle on linear uint4 index g (per 16-uint4 row-group = one 256B col):
// slot = (g&15) ^ (col&7); 2-way bank aliasing only (free). Involution.
static __device__ __forceinline__ int swz(int g) {
    return (g & ~15) | ((g & 15) ^ ((g >> 4) & 7));
}

// async global->LDS, 16 B per lane: lane l lands at lptr + l*16 (linear).
static __device__ __forceinline__ void gload_lds16(const uint4* g, uint4* l) {
    __builtin_amdgcn_global_load_lds(
        (const __attribute__((address_space(1))) void*)g,
        (__attribute__((address_space(3))) void*)l, 16, 0, 0);
}

// ---------- kernel 1: normalize rows, emit bf16 a_hat + pos_dist ----------
__global__ __launch_bounds__(256) void normalize_kernel(
    const float* __restrict__ anchor, const float* __restrict__ positive,
    unsigned short* __restrict__ a_hat, float* __restrict__ pos_ws,
    float* __restrict__ out)
{
    if (blockIdx.x == 0 && threadIdx.x == 0) *out = 0.0f;

    const int wave = threadIdx.x >> 6;
    const int lane = threadIdx.x & 63;
    const int row  = blockIdx.x * 4 + wave;

    const float2* arow = (const float2*)(anchor   + row * DIM);
    const float2* prow = (const float2*)(positive + row * DIM);
    float2 a = arow[lane];
    float2 p = prow[lane];

    float sa  = a.x * a.x + a.y * a.y;
    float sp  = p.x * p.x + p.y * p.y;
    float sap = a.x * p.x + a.y * p.y;
    #pragma unroll
    for (int off = 32; off; off >>= 1) {
        sa  += __shfl_xor(sa,  off);
        sp  += __shfl_xor(sp,  off);
        sap += __shfl_xor(sap, off);
    }
    float na  = fmaxf(sqrtf(sa), 1e-12f);
    float npn = fmaxf(sqrtf(sp), 1e-12f);
    float inv = 1.0f / na;

    ushort2 pack;
    pack.x = f2bf(a.x * inv);
    pack.y = f2bf(a.y * inv);
    ((ushort2*)a_hat)[row * 64 + lane] = pack;

    if (lane == 0)
        pos_ws[row] = 2.0f - 2.0f * sap / (na * npn);
}

// ---------- kernel 2: symmetric gram row/col-max, 256x256 tiles ----------
// Upper triangle of 32x32 panel grid: tile (rb,cc), cc in [rb,32). Block
// bid -> (rb,cc) static (no atomics). Tile is the unique writer of
// P[cc][its 256 rows] (row-max over its 256 cols) and Q[rb][its 256 cols]
// (col-max over its 256 rows; gram bit-exactly symmetric). Operand traffic
// = 528 tiles x 128 KB = 68 MB total (minimized vs 100-164 MB in R0/R3).
__global__ __launch_bounds__(256, 2) void gram_kernel(
    const unsigned short* __restrict__ a_hat, const int* __restrict__ labels,
    float* __restrict__ P, float* __restrict__ Q)
{
    const int tid  = threadIdx.x;
    const int lane = tid & 63;
    const int wave = tid >> 6;
    const int quad = lane >> 4;
    const int l15  = lane & 15;

    // triangle map: cum(rb) = rb*(65-rb)/2  (always even products)
    const int bid = blockIdx.x;
    int rb = (int)((65.0f - sqrtf(4225.0f - 8.0f * (float)bid)) * 0.5f);
    while (rb * (65 - rb) / 2 > bid) --rb;
    while ((rb + 1) * (64 - rb) / 2 <= bid) ++rb;
    const int cc = rb + (bid - rb * (65 - rb) / 2);

    const int rowBase = rb * 256 + wave * 64;   // this wave's 64 rows
    const int colBase = cc * 256;

    const uint4* A = (const uint4*)a_hat;       // row stride = 16 uint4 (256 B)
    const uint4* Gsrc = A + colBase * 16;       // B panel: 256 cols x 256 B

    __shared__ uint4  smem[4096];               // 64 KB B panel (swizzled)
    __shared__ float  wcol[4][256];             // per-wave col maxes

    // A fragments: 64 rows = 4 slices of 16; lane holds A[l15][quad*8 k-chunk]
    bf16x8 afrag[4][4];
    #pragma unroll
    for (int ms = 0; ms < 4; ++ms) {
        const int r = rowBase + ms * 16 + l15;
        #pragma unroll
        for (int k = 0; k < 4; ++k)
            afrag[ms][k] = __builtin_bit_cast(bf16x8, A[r * 16 + k * 4 + quad]);
    }

    // output-row labels: row = rowBase + ms*16 + quad*4 + e  (int4-aligned)
    int4 rlab[4];
    #pragma unroll
    for (int ms = 0; ms < 4; ++ms)
        rlab[ms] = *(const int4*)(labels + rowBase + ms * 16 + quad * 4);

    for (int rep = 0; rep < REPEAT; ++rep) {
        // stage B panel: linear LDS dest slot s, global source swz(s)
        // (involution) so that smem[swz(g)] == Gsrc[g] after the barrier.
        #pragma unroll
        for (int i = 0; i < 16; ++i) {
            const int s = i * 256 + wave * 64 + lane;
            gload_lds16(Gsrc + swz(s), &smem[i * 256 + wave * 64]);
        }
        __syncthreads();   // compiler drains vmcnt before s_barrier

        float gmax[4][4];
        #pragma unroll
        for (int ms = 0; ms < 4; ++ms)
            #pragma unroll
            for (int e = 0; e < 4; ++e)
                gmax[ms][e] = -4.0f;

        #pragma unroll
        for (int cb = 0; cb < 8; ++cb) {
            const int C = colBase + cb * 32;
            const int clab0 = labels[C + l15];
            const int clab1 = labels[C + 16 + l15];

            bf16x8 bfrag[2][4];
            #pragma unroll
            for (int ns = 0; ns < 2; ++ns) {
                const int c = ns * 16 + l15;
                #pragma unroll
                for (int k = 0; k < 4; ++k) {
                    const int g = cb * 512 + c * 16 + k * 4 + quad;
                    bfrag[ns][k] = __builtin_bit_cast(bf16x8, smem[swz(g)]);
                }
            }

            #pragma unroll
            for (int ns = 0; ns < 2; ++ns) {
                const int cl = ns ? clab1 : clab0;
                float cmax = -4.0f;              // col-max over this wave's 64 rows
                #pragma unroll
                for (int ms = 0; ms < 4; ++ms) {
                    floatx4 acc = {0.f, 0.f, 0.f, 0.f};
                    #pragma unroll
                    for (int k = 0; k < 4; ++k)
                        acc = __builtin_amdgcn_mfma_f32_16x16x32_bf16(
                                  afrag[ms][k], bfrag[ns][k], acc, 0, 0, 0);
                    #pragma unroll
                    for (int e = 0; e < 4; ++e) {
                        const int rle = (e == 0) ? rlab[ms].x : (e == 1) ? rlab[ms].y
                                      : (e == 2) ? rlab[ms].z : rlab[ms].w;
                        float v = (cl != rle) ? acc[e] : -4.0f;
                        gmax[ms][e] = fmaxf(gmax[ms][e], v);
                        cmax        = fmaxf(cmax, v);
                    }
                }
                cmax = fmaxf(cmax, __shfl_xor(cmax, 16));
                cmax = fmaxf(cmax, __shfl_xor(cmax, 32));
                if (quad == 0)
                    wcol[wave][cb * 32 + ns * 16 + l15] = cmax;
            }
        }

        // row flush: reduce the 16 cols per fragment row, store to P
        #pragma unroll
        for (int ms = 0; ms < 4; ++ms) {
            #pragma unroll
            for (int e = 0; e < 4; ++e) {
                float v = gmax[ms][e];
                #pragma unroll
                for (int off = 1; off < 16; off <<= 1)
                    v = fmaxf(v, __shfl_xor(v, off));
                if (l15 == 0)
                    P[cc * NROWS + rowBase + ms * 16 + quad * 4 + e] = v;
            }
        }

        // col flush: combine 4 waves' col maxes (all smem/wcol readers are
        // past this barrier, so next rep's stage writes are race-free)
        __syncthreads();
        {
            float m = fmaxf(fmaxf(wcol[0][tid], wcol[1][tid]),
                            fmaxf(wcol[2][tid], wcol[3][tid]));
            Q[rb * NROWS + colBase + tid] = m;
        }
    }
}

// ---------- kernel 3: gather partial maxes + final loss + mean ----------
// 512 blocks x 16 rows each; 16 lanes per row gather the 33 defined partials.
__global__ __launch_bounds__(256) void loss_kernel(
    const float* __restrict__ pos_ws, const float* __restrict__ P,
    const float* __restrict__ Q, float* __restrict__ out)
{
    const int tid  = threadIdx.x;
    const int lane = tid & 63;
    const int wave = tid >> 6;
    const int j    = tid & 15;                 // partial index within row
    const int g16  = tid >> 4;                 // 0..15 rows per block
    const int row  = blockIdx.x * 16 + g16;
    const int r    = row >> 8;                 // row's 256-panel

    float g = -4.0f;
    for (int c = r + j; c < 32; c += 16)       // P partials: cc in [r,32)
        g = fmaxf(g, P[c * NROWS + row]);
    for (int t = j; t <= r; t += 16)           // Q partials: rb in [0,r]
        g = fmaxf(g, Q[t * NROWS + row]);

    #pragma unroll
    for (int off = 1; off < 16; off <<= 1)
        g = fmaxf(g, __shfl_xor(g, off));

    float part = 0.0f;
    if (j == 0) {
        float neg = fmaxf(2.0f - 2.0f * g, 0.0f);
        part = fmaxf(pos_ws[row] - neg + 0.5f, 0.0f);
    }
    part += __shfl_xor(part, 16);
    part += __shfl_xor(part, 32);

    __shared__ float wsum[4];
    if (lane == 0) wsum[wave] = part;
    __syncthreads();
    if (tid == 0)
        atomicAdd(out, (wsum[0] + wsum[1] + wsum[2] + wsum[3]) * (1.0f / 8192.0f));
}

extern "C" void kernel_launch(void* const* d_in, const int* in_sizes, int n_in,
                              void* d_out, int out_size, void* d_ws, size_t ws_size,
                              hipStream_t stream) {
    const float* anchor   = (const float*)d_in[0];
    const float* positive = (const float*)d_in[1];
    const int*   labels   = (const int*)d_in[2];
    float* out = (float*)d_out;

    char* ws = (char*)d_ws;
    unsigned short* a_hat  = (unsigned short*)ws;                    // 2 MiB
    float*          pos_ws = (float*)(ws + 2 * 1024 * 1024);         // 32 KiB
    float*          P      = (float*)(ws + 4 * 1024 * 1024);         // 32*8192*4 = 1 MiB
    float*          Q      = (float*)(ws + 5 * 1024 * 1024);         // 32*8192*4 = 1 MiB

    normalize_kernel<<<NROWS / 4, 256, 0, stream>>>(anchor, positive, a_hat, pos_ws, out);
    gram_kernel<<<NTILE, 256, 0, stream>>>(a_hat, labels, P, Q);
    loss_kernel<<<NROWS / 16, 256, 0, stream>>>(pos_ws, P, Q, out);   // FIX: was /16/16 (32 blocks, 512 rows) -> 512 blocks, all 8192 rows
}

// Round 7
// 102.583 us; speedup vs baseline: 9.1938x; 9.1938x over previous
//
#include <hip/hip_runtime.h>
#include <stdint.h>

#define NROWS 8192
#define DIM 128
#define NTILE 1056   // 128-row x 256-col tiles, cc in [rb/2, 32), rb in [0,64)

typedef __bf16 bf16x8 __attribute__((ext_vector_type(8)));
typedef float floatx4 __attribute__((ext_vector_type(4)));

// ---------- helpers ----------
static __device__ __forceinline__ unsigned short f2bf(float f) {
    unsigned int u = __float_as_uint(f);
    unsigned int r = (u + 0x7FFFu + ((u >> 16) & 1u)) >> 16;   // RNE
    return (unsigned short)r;
}

// XOR swizzle on linear uint4 index g (16 uint4 = one 256 B column):
// slot = (g&15) ^ (col&7); 2-way bank aliasing only (free). Involution.
static __device__ __forceinline__ int swz(int g) {
    return (g & ~15) | ((g & 15) ^ ((g >> 4) & 7));
}

// async global->LDS, 16 B per lane: lane l lands at lptr + l*16 (linear).
static __device__ __forceinline__ void gload_lds16(const uint4* g, uint4* l) {
    __builtin_amdgcn_global_load_lds(
        (const __attribute__((address_space(1))) void*)g,
        (__attribute__((address_space(3))) void*)l, 16, 0, 0);
}

// tiles before row-panel rb: C(rb) = 32*rb - (rb^2 - 2rb + (rb&1))/4
static __device__ __forceinline__ int cumtile(int rb) {
    return 32 * rb - (rb * rb - 2 * rb + (rb & 1)) / 4;
}

// ---------- kernel 1: normalize rows, emit bf16 a_hat + pos_dist ----------
__global__ __launch_bounds__(256) void normalize_kernel(
    const float* __restrict__ anchor, const float* __restrict__ positive,
    unsigned short* __restrict__ a_hat, float* __restrict__ pos_ws,
    float* __restrict__ out)
{
    if (blockIdx.x == 0 && threadIdx.x == 0) *out = 0.0f;

    const int wave = threadIdx.x >> 6;
    const int lane = threadIdx.x & 63;
    const int row  = blockIdx.x * 4 + wave;

    const float2* arow = (const float2*)(anchor   + row * DIM);
    const float2* prow = (const float2*)(positive + row * DIM);
    float2 a = arow[lane];
    float2 p = prow[lane];

    float sa  = a.x * a.x + a.y * a.y;
    float sp  = p.x * p.x + p.y * p.y;
    float sap = a.x * p.x + a.y * p.y;
    #pragma unroll
    for (int off = 32; off; off >>= 1) {
        sa  += __shfl_xor(sa,  off);
        sp  += __shfl_xor(sp,  off);
        sap += __shfl_xor(sap, off);
    }
    float na  = fmaxf(sqrtf(sa), 1e-12f);
    float npn = fmaxf(sqrtf(sp), 1e-12f);
    float inv = 1.0f / na;

    ushort2 pack;
    pack.x = f2bf(a.x * inv);
    pack.y = f2bf(a.y * inv);
    ((ushort2*)a_hat)[row * 64 + lane] = pack;

    if (lane == 0)
        pos_ws[row] = 2.0f - 2.0f * sap / (na * npn);
}

// ---------- kernel 2: symmetric gram row/col-max, 128x256 tiles ----------
// REGISTER BUDGET RULE (R1/R2/R6 post-mortems): the allocator pins to the
// 128-VGPR occupancy step and spills anything above it into the MFMA loop
// (R6: VGPR=128, 841 MB scratch writes, 55us/rep). So the live set must fit
// UNDER 128: 32 rows/wave -> afrag[2][4]=32 regs, bfrag 32, gmax 8, rlab 8,
// ~110 total.
// Tile (rb,cc): rows [rb*128,+128), cols [cc*256,+256), cc in [rb/2, 32).
// Unique writer of P[cc][its 128 rows] (row-max over 256 cols) and
// Q[rb][its 256 cols] (col-max over 128 rows; gram bit-exactly symmetric).
__global__ __launch_bounds__(256) void gram_kernel(
    const unsigned short* __restrict__ a_hat, const int* __restrict__ labels,
    float* __restrict__ P, float* __restrict__ Q)
{
    const int tid  = threadIdx.x;
    const int lane = tid & 63;
    const int wave = tid >> 6;
    const int quad = lane >> 4;
    const int l15  = lane & 15;

    // triangle map
    const int bid = blockIdx.x;
    int rb = (int)(64.0f - 2.0f * sqrtf(1024.0f - (float)bid));
    rb = rb < 0 ? 0 : (rb > 63 ? 63 : rb);
    while (cumtile(rb) > bid) --rb;
    while (cumtile(rb + 1) <= bid) ++rb;
    const int cc = (rb >> 1) + (bid - cumtile(rb));

    const int rowBase = rb * 128 + wave * 32;   // this wave's 32 rows
    const int colBase = cc * 256;

    const uint4* A = (const uint4*)a_hat;       // row stride = 16 uint4 (256 B)
    const uint4* Gsrc = A + colBase * 16;       // B panel: 256 cols x 256 B

    __shared__ uint4  smem[4096];               // 64 KB B panel (swizzled)
    __shared__ float  wcol[4][256];             // per-wave col maxes

    // stage B panel: linear LDS dest slot s, global source swz(s) (involution)
    // so that smem[swz(g)] == Gsrc[g] after the barrier.
    #pragma unroll
    for (int i = 0; i < 16; ++i) {
        const int s = i * 256 + wave * 64 + lane;
        gload_lds16(Gsrc + swz(s), &smem[i * 256 + wave * 64]);
    }

    // A fragments: 32 rows = 2 slices of 16; lane holds A[l15][quad*8 k-chunk]
    bf16x8 afrag[2][4];
    #pragma unroll
    for (int ms = 0; ms < 2; ++ms) {
        const int r = rowBase + ms * 16 + l15;
        #pragma unroll
        for (int k = 0; k < 4; ++k)
            afrag[ms][k] = __builtin_bit_cast(bf16x8, A[r * 16 + k * 4 + quad]);
    }

    // output-row labels: row = rowBase + ms*16 + quad*4 + e
    int4 rlab[2];
    #pragma unroll
    for (int ms = 0; ms < 2; ++ms)
        rlab[ms] = *(const int4*)(labels + rowBase + ms * 16 + quad * 4);

    float gmax[2][4];
    #pragma unroll
    for (int ms = 0; ms < 2; ++ms)
        #pragma unroll
        for (int e = 0; e < 4; ++e)
            gmax[ms][e] = -4.0f;

    __syncthreads();   // compiler drains vmcnt (gload_lds) before s_barrier

    #pragma unroll
    for (int cb = 0; cb < 8; ++cb) {
        const int C = colBase + cb * 32;
        const int clab0 = labels[C + l15];
        const int clab1 = labels[C + 16 + l15];

        bf16x8 bfrag[2][4];
        #pragma unroll
        for (int ns = 0; ns < 2; ++ns) {
            const int c = ns * 16 + l15;
            #pragma unroll
            for (int k = 0; k < 4; ++k) {
                const int g = cb * 512 + c * 16 + k * 4 + quad;
                bfrag[ns][k] = __builtin_bit_cast(bf16x8, smem[swz(g)]);
            }
        }

        #pragma unroll
        for (int ns = 0; ns < 2; ++ns) {
            const int cl = ns ? clab1 : clab0;
            float cmax = -4.0f;                  // col-max over this wave's 32 rows
            #pragma unroll
            for (int ms = 0; ms < 2; ++ms) {
                floatx4 acc = {0.f, 0.f, 0.f, 0.f};
                #pragma unroll
                for (int k = 0; k < 4; ++k)
                    acc = __builtin_amdgcn_mfma_f32_16x16x32_bf16(
                              afrag[ms][k], bfrag[ns][k], acc, 0, 0, 0);
                #pragma unroll
                for (int e = 0; e < 4; ++e) {
                    const int rle = (e == 0) ? rlab[ms].x : (e == 1) ? rlab[ms].y
                                  : (e == 2) ? rlab[ms].z : rlab[ms].w;
                    float v = (cl != rle) ? acc[e] : -4.0f;
                    gmax[ms][e] = fmaxf(gmax[ms][e], v);
                    cmax        = fmaxf(cmax, v);
                }
            }
            cmax = fmaxf(cmax, __shfl_xor(cmax, 16));
            cmax = fmaxf(cmax, __shfl_xor(cmax, 32));
            if (quad == 0)
                wcol[wave][cb * 32 + ns * 16 + l15] = cmax;
        }
    }

    // row flush: reduce the 16 cols per fragment row, store to P
    #pragma unroll
    for (int ms = 0; ms < 2; ++ms) {
        #pragma unroll
        for (int e = 0; e < 4; ++e) {
            float v = gmax[ms][e];
            #pragma unroll
            for (int off = 1; off < 16; off <<= 1)
                v = fmaxf(v, __shfl_xor(v, off));
            if (l15 == 0)
                P[cc * NROWS + rowBase + ms * 16 + quad * 4 + e] = v;
        }
    }

    // col flush: combine 4 waves' col maxes, store to Q
    __syncthreads();
    {
        float m = fmaxf(fmaxf(wcol[0][tid], wcol[1][tid]),
                        fmaxf(wcol[2][tid], wcol[3][tid]));
        Q[rb * NROWS + colBase + tid] = m;
    }
}

// ---------- kernel 3: gather partial maxes + final loss + mean ----------
// 512 blocks x 16 rows each; 16 lanes per row gather the defined partials.
// Row i (r256 = i>>8): P[cc][i] for cc in [r256,32); Q[rb][i] for
// rb in [0, min(2*r256+1, 63)].
__global__ __launch_bounds__(256) void loss_kernel(
    const float* __restrict__ pos_ws, const float* __restrict__ P,
    const float* __restrict__ Q, float* __restrict__ out)
{
    const int tid  = threadIdx.x;
    const int lane = tid & 63;
    const int wave = tid >> 6;
    const int j    = tid & 15;                 // partial index within row
    const int g16  = tid >> 4;                 // 0..15 rows per block
    const int row  = blockIdx.x * 16 + g16;
    const int r256 = row >> 8;

    float g = -4.0f;
    for (int c = r256 + j; c < 32; c += 16)
        g = fmaxf(g, P[c * NROWS + row]);
    const int rmax = (2 * r256 + 1 < 63) ? 2 * r256 + 1 : 63;
    for (int t = j; t <= rmax; t += 16)
        g = fmaxf(g, Q[t * NROWS + row]);

    #pragma unroll
    for (int off = 1; off < 16; off <<= 1)
        g = fmaxf(g, __shfl_xor(g, off));

    float part = 0.0f;
    if (j == 0) {
        float neg = fmaxf(2.0f - 2.0f * g, 0.0f);
        part = fmaxf(pos_ws[row] - neg + 0.5f, 0.0f);
    }
    part += __shfl_xor(part, 16);
    part += __shfl_xor(part, 32);

    __shared__ float wsum[4];
    if (lane == 0) wsum[wave] = part;
    __syncthreads();
    if (tid == 0)
        atomicAdd(out, (wsum[0] + wsum[1] + wsum[2] + wsum[3]) * (1.0f / 8192.0f));
}

extern "C" void kernel_launch(void* const* d_in, const int* in_sizes, int n_in,
                              void* d_out, int out_size, void* d_ws, size_t ws_size,
                              hipStream_t stream) {
    const float* anchor   = (const float*)d_in[0];
    const float* positive = (const float*)d_in[1];
    const int*   labels   = (const int*)d_in[2];
    float* out = (float*)d_out;

    char* ws = (char*)d_ws;
    unsigned short* a_hat  = (unsigned short*)ws;                    // 2 MiB
    float*          pos_ws = (float*)(ws + 2 * 1024 * 1024);         // 32 KiB
    float*          P      = (float*)(ws + 4 * 1024 * 1024);         // 32*8192*4 = 1 MiB
    float*          Q      = (float*)(ws + 5 * 1024 * 1024);         // 64*8192*4 = 2 MiB

    normalize_kernel<<<NROWS / 4, 256, 0, stream>>>(anchor, positive, a_hat, pos_ws, out);
    gram_kernel<<<NTILE, 256, 0, stream>>>(a_hat, labels, P, Q);
    loss_kernel<<<NROWS / 16, 256, 0, stream>>>(pos_ws, P, Q, out);
}